// Round 5
// baseline (262.323 us; speedup 1.0000x reference)
//
#include <hip/hip_runtime.h>
#include <math.h>

#define SAMPLING_EPS 1e-5f
#define TCAND 2.8f          // prefilter threshold for N(0,1) logits; exact-fallback if invalid
#define SPLITS 16
#define BLOCK_A 256
#define BLOCK_B 256
#define CAPL 2048           // LDS candidate capacity (fallback path)
#define NBIN 4096           // fallback histogram bins (top 12 bits of monotone float)

// monotone float->uint transform (no NaNs expected)
__device__ __forceinline__ unsigned f2u(float f) {
  unsigned b = __float_as_uint(f);
  return (b & 0x80000000u) ? ~b : (b | 0x80000000u);
}

// combine two online-softmax partials: max, first-argmax, sum exp(x-m), sum exp((x-m)/t)
// (m==nm) guards avoid -inf - (-inf) = NaN on degenerate partials; expf(0)==1 otherwise.
__device__ __forceinline__ void redCombine(float& m, int& mi, float& sr, float& ss,
                                           float om, int omi, float osr, float oss,
                                           float its) {
  float nm = fmaxf(m, om);
  float e1 = (m == nm) ? 1.0f : expf(m - nm);
  float e2 = (om == nm) ? 1.0f : expf(om - nm);
  float f1 = (m == nm) ? 1.0f : expf((m - nm) * its);
  float f2 = (om == nm) ? 1.0f : expf((om - nm) * its);
  sr = sr * e1 + osr * e2;
  ss = ss * f1 + oss * f2;
  if (om > m || (om == m && omi < mi)) mi = omi;
  m = nm;
}

__device__ __forceinline__ void procElem(float x, int gidx,
                                         float& m, int& mi, float& sr, float& ss,
                                         float its, unsigned* crow,
                                         float* cvrow, int* cirow, int cap) {
  if (x > m) {
    float d = m - x;                  // < 0 (or -inf on first element)
    sr = sr * expf(d) + 1.0f;
    ss = ss * expf(d * its) + 1.0f;
    m = x; mi = gidx;
  } else {
    float d = x - m;                  // <= 0
    sr += expf(d);
    ss += expf(d * its);
  }
  if (x > TCAND) {
    unsigned p = atomicAdd(crow, 1u);
    if (p < (unsigned)cap) { cvrow[p] = x; cirow[p] = gidx; }
  }
}

__global__ void __launch_bounds__(BLOCK_A) sampler_pass1(
    const float* __restrict__ logits, const float* __restrict__ temperature,
    float4* __restrict__ partials, unsigned* __restrict__ cnt,
    float* __restrict__ candV, int* __restrict__ candI,
    int V, int cap) {
  const int row = blockIdx.y;
  const int chunk = blockIdx.x;
  const int S = gridDim.x;
  const int tid = threadIdx.x;
  const int CH = ((V + S - 1) / S + 3) & ~3;
  const int start = chunk * CH;
  const int end = (start + CH < V) ? (start + CH) : V;

  if (start >= end) {
    if (tid == 0) partials[row * S + chunk] = make_float4(-INFINITY, __int_as_float(0), 0.f, 0.f);
    return;
  }

  float temp = temperature[row];
  float ts = (temp < SAMPLING_EPS) ? 1.0f : temp;
  float its = 1.0f / ts;

  const float* lr = logits + (size_t)row * V;
  unsigned* crow = cnt + row;
  float* cvrow = candV + (size_t)row * cap;
  int* cirow = candI + (size_t)row * cap;

  float m = -INFINITY; int mi = 0; float sr = 0.f, ss = 0.f;

  const int n = end - start;
  const int n4 = n >> 2;
  const float4* p4 = reinterpret_cast<const float4*>(lr + start);
  for (int j = tid; j < n4; j += BLOCK_A) {
    float4 x4 = p4[j];
    int gbase = start + (j << 2);
    procElem(x4.x, gbase + 0, m, mi, sr, ss, its, crow, cvrow, cirow, cap);
    procElem(x4.y, gbase + 1, m, mi, sr, ss, its, crow, cvrow, cirow, cap);
    procElem(x4.z, gbase + 2, m, mi, sr, ss, its, crow, cvrow, cirow, cap);
    procElem(x4.w, gbase + 3, m, mi, sr, ss, its, crow, cvrow, cirow, cap);
  }
  for (int i = start + (n4 << 2) + tid; i < end; i += BLOCK_A) {
    procElem(lr[i], i, m, mi, sr, ss, its, crow, cvrow, cirow, cap);
  }

  // wave (64-lane) reduction
  for (int off = 32; off > 0; off >>= 1) {
    float om = __shfl_down(m, off);
    int omi = __shfl_down(mi, off);
    float osr = __shfl_down(sr, off);
    float oss = __shfl_down(ss, off);
    redCombine(m, mi, sr, ss, om, omi, osr, oss, its);
  }
  __shared__ float wm[BLOCK_A / 64], wsr[BLOCK_A / 64], wss[BLOCK_A / 64];
  __shared__ int wmi[BLOCK_A / 64];
  int wave = tid >> 6, lane = tid & 63;
  if (lane == 0) { wm[wave] = m; wmi[wave] = mi; wsr[wave] = sr; wss[wave] = ss; }
  __syncthreads();
  if (tid == 0) {
    for (int w = 1; w < BLOCK_A / 64; ++w)
      redCombine(m, mi, sr, ss, wm[w], wmi[w], wsr[w], wss[w], its);
    partials[row * S + chunk] = make_float4(m, __int_as_float(mi), sr, ss);
  }
}

__global__ void __launch_bounds__(BLOCK_B) sampler_finalize(
    const float* __restrict__ logits, const float* __restrict__ temperature,
    const float* __restrict__ top_p, const int* __restrict__ top_k,
    const float* __restrict__ gumbel,
    const float4* __restrict__ partials, const unsigned* __restrict__ cnt,
    const float* __restrict__ candV, const int* __restrict__ candI,
    float* __restrict__ out_ids, float* __restrict__ out_idx,
    float* __restrict__ out_lp, float* __restrict__ out_rank,
    int V, int S, int L, int cap, int NTOP) {
  const int row = blockIdx.x;
  const int tid = threadIdx.x;

  __shared__ float sV[CAPL];
  __shared__ int   sI[CAPL];
  __shared__ float sLp[CAPL];
  __shared__ float sSc[CAPL];
  __shared__ int   hist[NBIN];
  // sampling order (reference: argsort(-scaled), stable)
  __shared__ float posSc[128], posLp[128];
  __shared__ int   posIdx[128];
  // output order (reference: top_k(raw_logprobs))
  __shared__ float topLp[128];
  __shared__ int   topIdx[128];
  __shared__ float gscore[128], pexp[128];
  __shared__ float shM, shSr, shSs, shLpSel;
  __shared__ int   shGi;
  __shared__ unsigned uEdge;
  __shared__ int   fcnt;
  __shared__ int   wred[BLOCK_B / 64];

  float temp = temperature[row];
  float ts = (temp < SAMPLING_EPS) ? 1.0f : temp;

  // combine split partials
  if (tid == 0) {
    float m = -INFINITY; int mi = 0; float sr = 0.f, ss = 0.f;
    float its = 1.0f / ts;
    for (int s = 0; s < S; ++s) {
      float4 p = partials[row * S + s];
      redCombine(m, mi, sr, ss, p.x, __float_as_int(p.y), p.z, p.w, its);
    }
    shM = m; shGi = mi; shSr = sr; shSs = ss;
  }
  __syncthreads();
  const float M = shM;
  const float Ss = shSs;
  const float logSr = logf(shSr);

  // candidate set: fast path (prefiltered gather) or exact histogram fallback
  unsigned c = (cap > 0) ? cnt[row] : 0u;
  int C;
  if (cap > 0 && c >= (unsigned)NTOP && c <= (unsigned)cap) {
    C = (int)c;
    for (int i = tid; i < C; i += BLOCK_B) {
      float v = candV[(size_t)row * cap + i];
      int id = candI[(size_t)row * cap + i];
      sV[i] = v; sI[i] = id;
      sLp[i] = (v - M) - logSr;       // same formula as log_softmax (shift by max, subtract log-sum)
      sSc[i] = v / ts;                // same op as reference scaled = logits / temp_safe
    }
    __syncthreads();
  } else {
    const float* lr = logits + (size_t)row * V;
    for (int i = tid; i < NBIN; i += BLOCK_B) hist[i] = 0;
    __syncthreads();
    for (int i = tid; i < V; i += BLOCK_B) atomicAdd(&hist[f2u(lr[i]) >> 20], 1);
    __syncthreads();
    if (tid == 0) {
      int acc = 0, eb = 0;
      for (int b = NBIN - 1; b >= 0; --b) { acc += hist[b]; if (acc >= NTOP) { eb = b; break; } }
      uEdge = ((unsigned)eb) << 20;
      fcnt = 0;
    }
    __syncthreads();
    for (int i = tid; i < V; i += BLOCK_B) {
      float x = lr[i];
      if (f2u(x) >= uEdge) {
        int p = atomicAdd(&fcnt, 1);
        if (p < CAPL) { sV[p] = x; sI[p] = i; }
      }
    }
    __syncthreads();
    C = (fcnt < CAPL) ? fcnt : CAPL;
    for (int i = tid; i < C; i += BLOCK_B) {
      float v = sV[i];
      sLp[i] = (v - M) - logSr;
      sSc[i] = v / ts;
    }
    __syncthreads();
  }

  const int NT = (C < NTOP) ? C : NTOP;

  // dual rank-select over candidates:
  //  A) sampling order: (scaled desc, idx asc)  == stable argsort(-scaled)
  //  B) output order:   (logprob desc, idx asc) == lax.top_k(raw_logprobs)
  for (int i = tid; i < C; i += BLOCK_B) {
    float sci = sSc[i], lpi = sLp[i];
    int ii = sI[i];
    int rA = 0, rB = 0;
    for (int j = 0; j < C; ++j) {
      float scj = sSc[j], lpj = sLp[j];
      int ij = sI[j];
      rA += (scj > sci) || (scj == sci && ij < ii);
      rB += (lpj > lpi) || (lpj == lpi && ij < ii);
    }
    if (rA < NT) { posSc[rA] = sci; posLp[rA] = lpi; posIdx[rA] = ii; }
    if (rB < NT) { topLp[rB] = lpi; topIdx[rB] = ii; }
  }
  __syncthreads();

  // per-candidate prob + gumbel score in sampling order
  const float Msc = M / ts;
  if (tid < NT) {
    float sc = posSc[tid];
    gscore[tid] = sc + gumbel[(size_t)row * V + posIdx[tid]];
    pexp[tid] = expf(sc - Msc) / Ss;   // softmax over full V (denominator from pass 1)
  }
  __syncthreads();

  // serial top-p/top-k masked Gumbel-max (NT <= 128 iterations).
  // keep_p replicated as reference: inclusive cumsum then subtract.
  if (tid == 0) {
    int k = top_k[row];
    if (k < 1) k = 1;
    if (k > V) k = V;
    float tp = top_p[row];
    float cum = 0.f, best = -INFINITY;
    int bpos = 0;
    for (int j = 0; j < NT; ++j) {
      float p = pexp[j];
      cum += p;
      if (j < k && (cum - p) <= tp) {        // keep_k & keep_p
        float s = gscore[j];
        if (s > best) { best = s; bpos = j; }  // strict > => first-index argmax
      }
    }
    int sampled; float lpsel;
    if (temp < SAMPLING_EPS) {               // greedy row
      sampled = shGi;
      lpsel = 0.0f - logSr;                  // (M - M) - logSr
    } else {
      sampled = posIdx[bpos];
      lpsel = posLp[bpos];
    }
    shLpSel = lpsel;
    out_ids[row] = (float)sampled;
    out_idx[row * (L + 1)] = (float)sampled;
    out_lp[row * (L + 1)] = lpsel;
  }
  __syncthreads();

  // token rank: 1 + count(logprob > selected logprob) over all V
  // (every x > x_sel is in the candidate set, so counting over C is exact)
  float lpsel = shLpSel;
  int cg = 0;
  for (int i = tid; i < C; i += BLOCK_B) cg += (sLp[i] > lpsel) ? 1 : 0;
  for (int off = 32; off > 0; off >>= 1) cg += __shfl_down(cg, off);
  if ((tid & 63) == 0) wred[tid >> 6] = cg;
  __syncthreads();
  if (tid == 0) {
    int t = 0;
    for (int w = 0; w < BLOCK_B / 64; ++w) t += wred[w];
    out_rank[row] = (float)(t + 1);
  }

  // top-L logprobs + indices (output order)
  if (tid < L && tid < NT) {
    out_idx[row * (L + 1) + 1 + tid] = (float)topIdx[tid];
    out_lp[row * (L + 1) + 1 + tid] = topLp[tid];
  }
}

extern "C" void kernel_launch(void* const* d_in, const int* in_sizes, int n_in,
                              void* d_out, int out_size, void* d_ws, size_t ws_size,
                              hipStream_t stream) {
  const float* logits      = (const float*)d_in[0];
  const float* temperature = (const float*)d_in[1];
  const float* top_p       = (const float*)d_in[2];
  const int*   top_k       = (const int*)d_in[3];
  const float* gumbel      = (const float*)d_in[4];

  const int B = in_sizes[1];
  const int V = in_sizes[0] / B;
  int L = out_size / (2 * B) - 2;          // out = B + B(L+1) + B(L+1) + B
  if (L < 0) L = 0;
  int NTOP = 64;
  if (L > 64) NTOP = (L <= 128) ? L : 128;

  // workspace layout: counters | partials | candV | candI — degrade gracefully if small
  int S = SPLITS;
  unsigned char* ws = (unsigned char*)d_ws;
  size_t cntBytes = ((size_t)B * 4 + 255) & ~(size_t)255;
  while (S > 1 && cntBytes + (size_t)B * S * sizeof(float4) > ws_size) S >>= 1;
  unsigned* cnt = (unsigned*)ws;
  float4* partials = (float4*)(ws + cntBytes);
  size_t off = cntBytes + (size_t)B * S * sizeof(float4);
  off = (off + 255) & ~(size_t)255;
  size_t rem = (ws_size > off) ? (ws_size - off) : 0;
  int cap = (int)(rem / ((size_t)B * 8));
  if (cap > 1024) cap = 1024;
  if (cap < 0) cap = 0;
  float* candV = (float*)(ws + off);
  int*   candI = (int*)(ws + off + (size_t)B * cap * 4);

  hipMemsetAsync(cnt, 0, (size_t)B * 4, stream);

  dim3 gA(S, B);
  sampler_pass1<<<gA, BLOCK_A, 0, stream>>>(logits, temperature, partials, cnt,
                                            candV, candI, V, cap);

  float* out_f = (float*)d_out;
  float* out_ids = out_f;
  float* out_idx = out_f + B;
  float* out_lp = out_f + B + B * (L + 1);
  float* out_rank = out_f + B + 2 * B * (L + 1);

  sampler_finalize<<<B, BLOCK_B, 0, stream>>>(logits, temperature, top_p, top_k, gumbel,
                                              partials, cnt, candV, candI,
                                              out_ids, out_idx, out_lp, out_rank,
                                              V, S, L, cap, NTOP);
}